// Round 8
// baseline (530.211 us; speedup 1.0000x reference)
//
#include <hip/hip_runtime.h>
#include <math.h>

// S=64 segments(seq), B=256 atoms(batch), N=16384 rows, D=128, H=8, HD=16,
// DFF=2048, NL=6.  One fused kernel per transformer layer. FFN uses MFMA
// chaining: ff1 transposed (16x16x32 bf16) -> registers -> ff2 (16x16x16 f16,
// C-layout == B-layout) with NO H LDS round-trip. s2s: f16 fdot2, reg weights.

typedef __attribute__((ext_vector_type(8))) short bf16x8;
typedef __attribute__((ext_vector_type(4))) float f32x4;
typedef _Float16 __attribute__((ext_vector_type(2))) h16x2;
typedef _Float16 __attribute__((ext_vector_type(4))) f16x4;

__device__ __forceinline__ unsigned short f2bf(float f) {
  union { float f; unsigned u; } x; x.f = f;
  unsigned r = x.u + 0x7fff + ((x.u >> 16) & 1);
  return (unsigned short)(r >> 16);
}
__device__ __forceinline__ float bf2f(unsigned short u) {
  union { unsigned u; float f; } x; x.u = ((unsigned)u) << 16;
  return x.f;
}
__device__ __forceinline__ float uplo(unsigned u) {
  union { unsigned u; float f; } x; x.u = u << 16; return x.f;
}
__device__ __forceinline__ float uphi(unsigned u) {
  union { unsigned u; float f; } x; x.u = u & 0xffff0000u; return x.f;
}
__device__ __forceinline__ unsigned short f2h(float f) {
  union { _Float16 h; unsigned short s; } x; x.h = (_Float16)f; return x.s;
}
__device__ __forceinline__ unsigned packh(float a, float b) {
  return (unsigned)f2h(a) | ((unsigned)f2h(b) << 16);
}
__device__ __forceinline__ float hlo(unsigned u) {
  union { unsigned short s; _Float16 h; } x; x.s = (unsigned short)(u & 0xffff);
  return (float)x.h;
}
__device__ __forceinline__ float hhi(unsigned u) {
  union { unsigned short s; _Float16 h; } x; x.s = (unsigned short)(u >> 16);
  return (float)x.h;
}
__device__ __forceinline__ float fdot2u(unsigned a, unsigned b, float c) {
#if __has_builtin(__builtin_amdgcn_fdot2)
  union U { unsigned u; h16x2 h; };
  U x, y; x.u = a; y.u = b;
  return __builtin_amdgcn_fdot2(x.h, y.h, c, false);
#else
  return c + hlo(a) * hlo(b) + hhi(a) * hhi(b);
#endif
}
__device__ __forceinline__ float sigf(float x) { return 1.f / (1.f + expf(-x)); }

// async 16B global->LDS; LDS base wave-uniform (+ lane*16 implicit).
__device__ __forceinline__ void gl2lds16(const void* g, void* l) {
  __builtin_amdgcn_global_load_lds(
      (const __attribute__((address_space(1))) unsigned int*)g,
      (__attribute__((address_space(3))) unsigned int*)l, 16, 0, 0);
}

// ---------------------------------------------------------------------------
// weight conversion: bf16 (aiw, aow, w1), f16 (w2, wih, whh, mwih).
// aiw 294912 | aow 98304 | w1 1572864 | w2 1572864
// | wih 131072 | whh 65536 | mwih 131072   -> total 3866624
// ---------------------------------------------------------------------------
__global__ __launch_bounds__(256) void convw_kernel(
    const float* __restrict__ aiw, const float* __restrict__ aow,
    const float* __restrict__ w1, const float* __restrict__ w2,
    const float* __restrict__ wih, const float* __restrict__ whh,
    const float* __restrict__ mwih,
    unsigned short* __restrict__ o0, unsigned short* __restrict__ o1,
    unsigned short* __restrict__ o2, unsigned short* __restrict__ o3,
    unsigned short* __restrict__ o4, unsigned short* __restrict__ o5,
    unsigned short* __restrict__ o6) {
  int i = blockIdx.x * 256 + threadIdx.x;
  if (i < 294912) {
    o0[i] = f2bf(aiw[i]);
  } else if (i < 393216) {
    int j = i - 294912; o1[j] = f2bf(aow[j]);
  } else if (i < 1966080) {
    int j = i - 393216; o2[j] = f2bf(w1[j]);
  } else if (i < 3538944) {
    int j = i - 1966080; o3[j] = f2h(w2[j]);      // w2 -> f16 (chained MFMA)
  } else if (i < 3670016) {
    int j = i - 3538944; o4[j] = f2h(wih[j]);
  } else if (i < 3735552) {
    int j = i - 3670016; o5[j] = f2h(whh[j]);
  } else {
    int j = i - 3735552; o6[j] = f2h(mwih[j]);
  }
}

// ---------------------------------------------------------------------------
// lin0: x = relu(data @ w^T + b), writes fp32 x and bf16 xb
// ---------------------------------------------------------------------------
__global__ __launch_bounds__(256) void lin0_kernel(
    const float* __restrict__ data, const float* __restrict__ w,
    const float* __restrict__ b, float* __restrict__ x,
    unsigned short* __restrict__ xb) {
  int i = blockIdx.x * 256 + threadIdx.x;
  int n = i >> 7, d = i & 127;
  float v = b[d] + data[n * 3 + 0] * w[d * 3 + 0]
                 + data[n * 3 + 1] * w[d * 3 + 1]
                 + data[n * 3 + 2] * w[d * 3 + 2];
  v = fmaxf(v, 0.0f);
  x[i] = v;
  xb[i] = f2bf(v);
}

// ---------------------------------------------------------------------------
// Fused transformer LAYER: block = atom b (256 blocks), 512 threads, 8 waves.
// Attention as R7. FFN: wave pair (2t,2t+1) owns s-tile t, splits hidden;
// ff1^T (bf16 K32) -> regs -> ff2^T (f16 K16, chained) -> pairwise LDS
// reduction -> in-wave LN2 -> global (transposed scatter, 16B granules).
// ---------------------------------------------------------------------------
__global__ __launch_bounds__(512) void layer_kernel(
    const unsigned short* __restrict__ xbg,
    const unsigned short* __restrict__ wqkv, const float* __restrict__ bqkv,
    const unsigned short* __restrict__ wout, const float* __restrict__ bout,
    const float* __restrict__ ln1g, const float* __restrict__ ln1b,
    const unsigned short* __restrict__ w1, const float* __restrict__ b1,
    const unsigned short* __restrict__ w2, const float* __restrict__ b2,
    const float* __restrict__ ln2g, const float* __restrict__ ln2b,
    float* __restrict__ xio, unsigned short* __restrict__ xbo) {
  __shared__ __align__(16) unsigned short Xs[64 * 128];   // 16 KB
  __shared__ __align__(16) unsigned short Ws[256 * 128];  // 64 KB
  __shared__ __align__(16) unsigned short U1[128 * 128];  // 32 KB
  __shared__ __align__(16) unsigned short U2[128 * 128];  // 32 KB
  __shared__ __align__(16) uint4 zchunk;
  __shared__ float psum[8][64], psq[8][64];
  __shared__ float2 stats[64];

  unsigned short* Qs = U1;            // 64x128 (attention)
  unsigned short* Ks2 = U1 + 8192;    // 64x128
  unsigned short* VT = U2;            // 128x64
  unsigned short* AOs = U2 + 8192;    // 64x128

  int tid = threadIdx.x, w = tid >> 6, lane = tid & 63;
  int b = blockIdx.x;
  int r4 = lane >> 4, cs = lane & 15;
  int fr = lane & 15, fq = lane >> 4;

  if (tid == 0) zchunk = make_uint4(0u, 0u, 0u, 0u);

  // ---- phase 0: stage x tile + Wq+Wk (wqkv rows 0..255) ----
#pragma unroll
  for (int i = 0; i < 2; i++) {
    int issue = w * 2 + i;
    int row = issue * 4 + r4;  // s index
    int g = cs ^ (row & 7);
    gl2lds16(xbg + (size_t)(row * 256 + b) * 128 + g * 8,
             (char*)Xs + issue * 1024);
  }
#pragma unroll
  for (int i = 0; i < 8; i++) {
    int issue = w * 8 + i;
    int row = issue * 4 + r4;
    int g = cs ^ (row & 7);
    gl2lds16(wqkv + (size_t)row * 128 + g * 8, (char*)Ws + issue * 1024);
  }
  __syncthreads();

  // ---- phase 1: Q,K = x @ Wqk^T + bias -> Qs/Ks2 ----
  {
    f32x4 acc[4][2];
#pragma unroll
    for (int i = 0; i < 4; i++)
#pragma unroll
      for (int j = 0; j < 2; j++) acc[i][j] = (f32x4){0.f, 0.f, 0.f, 0.f};
#pragma unroll
    for (int ks = 0; ks < 4; ks++) {
      bf16x8 af[4], bf[2];
#pragma unroll
      for (int mi = 0; mi < 4; mi++) {
        int row = mi * 16 + fr;
        int kq = (ks * 4 + fq) ^ (row & 7);
        af[mi] = *(const bf16x8*)(Xs + row * 128 + kq * 8);
      }
#pragma unroll
      for (int ni = 0; ni < 2; ni++) {
        int wr = (w * 2 + ni) * 16 + fr;
        int kq = (ks * 4 + fq) ^ (wr & 7);
        bf[ni] = *(const bf16x8*)(Ws + wr * 128 + kq * 8);
      }
#pragma unroll
      for (int mi = 0; mi < 4; mi++)
#pragma unroll
        for (int ni = 0; ni < 2; ni++)
          acc[mi][ni] = __builtin_amdgcn_mfma_f32_16x16x32_bf16(
              af[mi], bf[ni], acc[mi][ni], 0, 0, 0);
    }
#pragma unroll
    for (int ni = 0; ni < 2; ni++) {
      int c = (w * 2 + ni) * 16 + fr;  // 0..255
      float bv = bqkv[c];
      unsigned short* dst = (c < 128) ? Qs : Ks2;
      int cc = c & 127;
#pragma unroll
      for (int mi = 0; mi < 4; mi++)
#pragma unroll
        for (int r = 0; r < 4; r++) {
          int row = mi * 16 + fq * 4 + r;
          dst[row * 128 + (((cc >> 3) ^ (row & 7)) << 3) + (cc & 7)] =
              f2bf(acc[mi][ni][r] + bv);
        }
    }
  }
  __syncthreads();

  // ---- stage Wv (wqkv rows 256..383) into Ws rows 0..127 ----
#pragma unroll
  for (int i = 0; i < 4; i++) {
    int issue = w * 4 + i;
    int row = issue * 4 + r4;
    int g = cs ^ (row & 7);
    gl2lds16(wqkv + (size_t)(256 + row) * 128 + g * 8, (char*)Ws + issue * 1024);
  }
  __syncthreads();

  // ---- phase 2: V = x @ Wv^T + bias -> VT[feature][s] ----
  {
    f32x4 acc[4];
#pragma unroll
    for (int i = 0; i < 4; i++) acc[i] = (f32x4){0.f, 0.f, 0.f, 0.f};
#pragma unroll
    for (int ks = 0; ks < 4; ks++) {
      bf16x8 af[4], bf;
#pragma unroll
      for (int mi = 0; mi < 4; mi++) {
        int row = mi * 16 + fr;
        int kq = (ks * 4 + fq) ^ (row & 7);
        af[mi] = *(const bf16x8*)(Xs + row * 128 + kq * 8);
      }
      {
        int wr = w * 16 + fr;
        int kq = (ks * 4 + fq) ^ (wr & 7);
        bf = *(const bf16x8*)(Ws + wr * 128 + kq * 8);
      }
#pragma unroll
      for (int mi = 0; mi < 4; mi++)
        acc[mi] = __builtin_amdgcn_mfma_f32_16x16x32_bf16(af[mi], bf, acc[mi],
                                                          0, 0, 0);
    }
    int f = w * 16 + fr;
    float bv = bqkv[256 + f];
#pragma unroll
    for (int mi = 0; mi < 4; mi++)
#pragma unroll
      for (int r = 0; r < 4; r++) {
        int srow = mi * 16 + fq * 4 + r;
        VT[f * 64 + (((srow >> 3) ^ (f & 7)) << 3) + (srow & 7)] =
            f2bf(acc[mi][r] + bv);
      }
  }
  __syncthreads();

  // ---- phase 3: per-wave head attention (head h = w), P in Ws ----
  {
    int h = w;
    unsigned short* Pb = Ws + w * 4096;  // 8 KB per wave
    f32x4 sc[4][4];
#pragma unroll
    for (int i = 0; i < 4; i++)
#pragma unroll
      for (int j = 0; j < 4; j++) sc[i][j] = (f32x4){0.f, 0.f, 0.f, 0.f};
    {
      bf16x8 af[4], bf[4];
#pragma unroll
      for (int mi = 0; mi < 4; mi++) {
        int row = mi * 16 + fr;
        const unsigned short* pa =
            (fq < 2) ? (Qs + row * 128 + (((h * 2 + fq) ^ (row & 7)) << 3))
                     : (const unsigned short*)&zchunk;
        af[mi] = *(const bf16x8*)pa;
      }
#pragma unroll
      for (int ti = 0; ti < 4; ti++) {
        int trow = ti * 16 + fr;
        const unsigned short* pb =
            (fq < 2) ? (Ks2 + trow * 128 + (((h * 2 + fq) ^ (trow & 7)) << 3))
                     : (const unsigned short*)&zchunk;
        bf[ti] = *(const bf16x8*)pb;
      }
#pragma unroll
      for (int mi = 0; mi < 4; mi++)
#pragma unroll
        for (int ti = 0; ti < 4; ti++)
          sc[mi][ti] = __builtin_amdgcn_mfma_f32_16x16x32_bf16(
              af[mi], bf[ti], sc[mi][ti], 0, 0, 0);
    }
#pragma unroll
    for (int mi = 0; mi < 4; mi++) {
#pragma unroll
      for (int r = 0; r < 4; r++) {
        float m = -1e30f;
#pragma unroll
        for (int ti = 0; ti < 4; ti++) m = fmaxf(m, sc[mi][ti][r]);
        m = fmaxf(m, __shfl_xor(m, 1, 64));
        m = fmaxf(m, __shfl_xor(m, 2, 64));
        m = fmaxf(m, __shfl_xor(m, 4, 64));
        m = fmaxf(m, __shfl_xor(m, 8, 64));
        m *= 0.25f;
        float ss = 0.f;
#pragma unroll
        for (int ti = 0; ti < 4; ti++) {
          float p = expf(sc[mi][ti][r] * 0.25f - m);
          sc[mi][ti][r] = p;
          ss += p;
        }
        ss += __shfl_xor(ss, 1, 64);
        ss += __shfl_xor(ss, 2, 64);
        ss += __shfl_xor(ss, 4, 64);
        ss += __shfl_xor(ss, 8, 64);
        float inv = 1.f / ss;
        int prow = mi * 16 + fq * 4 + r;
#pragma unroll
        for (int ti = 0; ti < 4; ti++) {
          int t = ti * 16 + fr;
          Pb[prow * 64 + (((t >> 3) ^ (prow & 7)) << 3) + (t & 7)] =
              f2bf(sc[mi][ti][r] * inv);
        }
      }
    }
    // PV
    f32x4 po[4];
#pragma unroll
    for (int i = 0; i < 4; i++) po[i] = (f32x4){0.f, 0.f, 0.f, 0.f};
#pragma unroll
    for (int ks2 = 0; ks2 < 2; ks2++) {
      bf16x8 af[4], bf;
#pragma unroll
      for (int si = 0; si < 4; si++) {
        int prow = si * 16 + fr;
        int kq = (ks2 * 4 + fq) ^ (prow & 7);
        af[si] = *(const bf16x8*)(Pb + prow * 64 + kq * 8);
      }
      {
        int vrow = h * 16 + fr;
        int kq = (ks2 * 4 + fq) ^ (vrow & 7);
        bf = *(const bf16x8*)(VT + vrow * 64 + kq * 8);
      }
#pragma unroll
      for (int si = 0; si < 4; si++)
        po[si] = __builtin_amdgcn_mfma_f32_16x16x32_bf16(af[si], bf, po[si],
                                                         0, 0, 0);
    }
#pragma unroll
    for (int si = 0; si < 4; si++)
#pragma unroll
      for (int r = 0; r < 4; r++) {
        int arow = si * 16 + fq * 4 + r;
        int c = h * 16 + fr;
        AOs[arow * 128 + (((c >> 3) ^ (arow & 7)) << 3) + (c & 7)] =
            f2bf(po[si][r]);
      }
  }
  __syncthreads();

  // ---- stage Wout into Ws rows 0..127 ----
#pragma unroll
  for (int i = 0; i < 4; i++) {
    int issue = w * 4 + i;
    int row = issue * 4 + r4;
    int g = cs ^ (row & 7);
    gl2lds16(wout + (size_t)row * 128 + g * 8, (char*)Ws + issue * 1024);
  }
  __syncthreads();

  // ---- phase 4: v = x + ao @ Wout^T + bias ; LN1 -> Xs (bf16) ----
  {
    f32x4 acc[4];
#pragma unroll
    for (int i = 0; i < 4; i++) acc[i] = (f32x4){0.f, 0.f, 0.f, 0.f};
#pragma unroll
    for (int ks = 0; ks < 4; ks++) {
      bf16x8 af[4], bf;
#pragma unroll
      for (int si = 0; si < 4; si++) {
        int row = si * 16 + fr;
        int kq = (ks * 4 + fq) ^ (row & 7);
        af[si] = *(const bf16x8*)(AOs + row * 128 + kq * 8);
      }
      {
        int wr = w * 16 + fr;
        int kq = (ks * 4 + fq) ^ (wr & 7);
        bf = *(const bf16x8*)(Ws + wr * 128 + kq * 8);
      }
#pragma unroll
      for (int si = 0; si < 4; si++)
        acc[si] = __builtin_amdgcn_mfma_f32_16x16x32_bf16(af[si], bf, acc[si],
                                                          0, 0, 0);
    }
    int c = w * 16 + fr;
    float bv = bout[c];
    float vv4[4][4];
    float sums[4][4], sqs[4][4];
#pragma unroll
    for (int si = 0; si < 4; si++)
#pragma unroll
      for (int r = 0; r < 4; r++) {
        int row = si * 16 + fq * 4 + r;
        float v = acc[si][r] + bv + xio[(size_t)(row * 256 + b) * 128 + c];
        vv4[si][r] = v;
        sums[si][r] = v;
        sqs[si][r] = v * v;
      }
#pragma unroll
    for (int d = 1; d < 16; d <<= 1) {
#pragma unroll
      for (int si = 0; si < 4; si++)
#pragma unroll
        for (int r = 0; r < 4; r++) {
          sums[si][r] += __shfl_xor(sums[si][r], d, 64);
          sqs[si][r] += __shfl_xor(sqs[si][r], d, 64);
        }
    }
    if (fr == 0) {
#pragma unroll
      for (int si = 0; si < 4; si++)
#pragma unroll
        for (int r = 0; r < 4; r++) {
          int row = si * 16 + fq * 4 + r;
          psum[w][row] = sums[si][r];
          psq[w][row] = sqs[si][r];
        }
    }
    __syncthreads();  // A: phase-4 mfma done everywhere -> Ws/U1 reusable

    // FFN prologue staging: W1(0)->Ws[0], W2(0)->U1 (drains at barrier B)
#pragma unroll
    for (int i = 0; i < 4; i++) {
      int issue = w * 4 + i;
      int row = issue * 4 + r4;
      int g = cs ^ (row & 7);
      gl2lds16(w1 + (size_t)row * 128 + g * 8, (char*)Ws + issue * 1024);
      gl2lds16(w2 + (size_t)row * 2048 + g * 8, (char*)U1 + issue * 1024);
    }
    if (tid < 64) {
      float S = 0.f, Q = 0.f;
#pragma unroll
      for (int ww = 0; ww < 8; ww++) { S += psum[ww][tid]; Q += psq[ww][tid]; }
      float m = S * (1.f / 128.f);
      float var = Q * (1.f / 128.f) - m * m;
      stats[tid] = make_float2(m, rsqrtf(var + 1e-5f));
    }
    __syncthreads();  // B
    float gl = ln1g[c], bl = ln1b[c];
#pragma unroll
    for (int si = 0; si < 4; si++)
#pragma unroll
      for (int r = 0; r < 4; r++) {
        int row = si * 16 + fq * 4 + r;
        float2 st2 = stats[row];
        float y = (vv4[si][r] - st2.x) * st2.y * gl + bl;
        Xs[row * 128 + (((c >> 3) ^ (row & 7)) << 3) + (c & 7)] = f2bf(y);
      }
  }
  __syncthreads();  // C: Xs (LN1 output) published

  // ---- FFN: chained MFMA, no H round-trip ----
  int st = w >> 1;   // s-tile (s = st*16 .. +16)
  int hh = w & 1;    // hidden half within each 128-chunk

  f32x4 acc2[8];
#pragma unroll
  for (int i = 0; i < 8; i++) acc2[i] = (f32x4){0.f, 0.f, 0.f, 0.f};

  for (int c = 0; c < 16; c++) {
    const unsigned short* W1cur = Ws + (c & 1) * 16384;
    const unsigned short* W2cur = (c & 1) ? U2 : U1;
    if (c < 15) {  // stage next chunk into the other buffers (async)
#pragma unroll
      for (int i = 0; i < 4; i++) {
        int issue = w * 4 + i;
        int row = issue * 4 + r4;
        int g = cs ^ (row & 7);
        gl2lds16(w1 + (size_t)((c + 1) * 128 + row) * 128 + g * 8,
                 (char*)Ws + ((c + 1) & 1) * 32768 + issue * 1024);
        gl2lds16(w2 + (size_t)row * 2048 + (c + 1) * 128 + g * 8,
                 (char*)((c & 1) ? U1 : U2) + issue * 1024);
      }
    }
    // ff1 transposed: D1[h][s] = W1[h][:] . x[s][:]  (A=W1, B=Xs)
    f16x4 hf[4];
#pragma unroll
    for (int ht = 0; ht < 4; ht++) {
      f32x4 a1 = (f32x4){0.f, 0.f, 0.f, 0.f};
      int hrow = hh * 64 + ht * 16 + fr;
      int srow = st * 16 + fr;
#pragma unroll
      for (int ks = 0; ks < 4; ks++) {
        bf16x8 aw = *(const bf16x8*)(W1cur + hrow * 128 +
                                     (((ks * 4 + fq) ^ (hrow & 7)) << 3));
        bf16x8 bx = *(const bf16x8*)(Xs + srow * 128 +
                                     (((ks * 4 + fq) ^ (srow & 7)) << 3));
        a1 = __builtin_amdgcn_mfma_f32_16x16x32_bf16(aw, bx, a1, 0, 0, 0);
      }
      float4 b1v = *(const float4*)(b1 + c * 128 + hh * 64 + ht * 16 + fq * 4);
      hf[ht][0] = (_Float16)fmaxf(a1[0] + b1v.x, 0.f);
      hf[ht][1] = (_Float16)fmaxf(a1[1] + b1v.y, 0.f);
      hf[ht][2] = (_Float16)fmaxf(a1[2] + b1v.z, 0.f);
      hf[ht][3] = (_Float16)fmaxf(a1[3] + b1v.w, 0.f);
    }
    // ff2 transposed: acc2[ot][o][s] += W2[o][h] * H  (A=W2 f16, B=hf)
#pragma unroll
    for (int ot = 0; ot < 8; ot++) {
#pragma unroll
      for (int ht = 0; ht < 4; ht++) {
        int orow = ot * 16 + fr;
        int c16 = hh * 8 + ht * 2 + (fq >> 1);
        f16x4 wv = *(const f16x4*)(W2cur + orow * 128 +
                                   ((c16 ^ (orow & 7)) << 3) + (fq & 1) * 4);
        acc2[ot] = __builtin_amdgcn_mfma_f32_16x16x16f16(wv, hf[ht], acc2[ot],
                                                         0, 0, 0);
      }
    }
    __syncthreads();  // covers staging drain + buffer swap
  }

  // ---- pairwise cross-wave reduction (hidden halves) ----
  if (hh == 1) {
    float* slot = (float*)Ws + st * 2048;  // 8 KB per s-tile
#pragma unroll
    for (int ot = 0; ot < 8; ot++)
      *(f32x4*)(slot + ot * 256 + lane * 4) = acc2[ot];
  }
  __syncthreads();
  if (hh == 0) {
    const float* slot = (const float*)Ws + st * 2048;
#pragma unroll
    for (int ot = 0; ot < 8; ot++)
      acc2[ot] += *(const f32x4*)(slot + ot * 256 + lane * 4);

    // LN2 epilogue (even waves): lane holds all 128 o for s = st*16+fr.
    int s = st * 16 + fr;
    float vals[8][4];
    float sum = 0.f, sq = 0.f;
#pragma unroll
    for (int ot = 0; ot < 8; ot++) {
      int o0 = ot * 16 + fq * 4;
      float4 b2v = *(const float4*)(b2 + o0);
      int cx = ((o0 >> 3) ^ (s & 7));
      ushort4 ru = *(const ushort4*)(Xs + s * 128 + (cx << 3) + (fq & 1) * 4);
      float v0 = acc2[ot][0] + b2v.x + bf2f(ru.x);
      float v1 = acc2[ot][1] + b2v.y + bf2f(ru.y);
      float v2 = acc2[ot][2] + b2v.z + bf2f(ru.z);
      float v3 = acc2[ot][3] + b2v.w + bf2f(ru.w);
      vals[ot][0] = v0; vals[ot][1] = v1; vals[ot][2] = v2; vals[ot][3] = v3;
      sum += (v0 + v1) + (v2 + v3);
      sq += (v0 * v0 + v1 * v1) + (v2 * v2 + v3 * v3);
    }
    sum += __shfl_xor(sum, 16, 64); sum += __shfl_xor(sum, 32, 64);
    sq += __shfl_xor(sq, 16, 64);   sq += __shfl_xor(sq, 32, 64);
    float mean = sum * (1.f / 128.f);
    float inv = rsqrtf(sq * (1.f / 128.f) - mean * mean + 1e-5f);
    size_t rowbase = (size_t)(s * 256 + b) * 128;
#pragma unroll
    for (int ot = 0; ot < 8; ot++) {
      int o0 = ot * 16 + fq * 4;
      float4 g4 = *(const float4*)(ln2g + o0);
      float4 bb4 = *(const float4*)(ln2b + o0);
      float y0 = (vals[ot][0] - mean) * inv * g4.x + bb4.x;
      float y1 = (vals[ot][1] - mean) * inv * g4.y + bb4.y;
      float y2 = (vals[ot][2] - mean) * inv * g4.z + bb4.z;
      float y3 = (vals[ot][3] - mean) * inv * g4.w + bb4.w;
      *(float4*)(xio + rowbase + o0) = make_float4(y0, y1, y2, y3);
      ushort4 ub;
      ub.x = f2bf(y0); ub.y = f2bf(y1); ub.z = f2bf(y2); ub.w = f2bf(y3);
      *(ushort4*)(xbo + rowbase + o0) = ub;
    }
  }
}

// ---------------------------------------------------------------------------
// Set2Set (6 steps) + memory LSTM + lin1 + lin3. One 512-thread block per
// segment (64 blocks -> 1/CU). (512,1): 256-VGPR cap keeps the 48 uint4 gate
// weights register-resident.
// ---------------------------------------------------------------------------
__global__ __launch_bounds__(512, 1) void s2s_kernel(
    const unsigned short* __restrict__ xb,
    const unsigned short* __restrict__ wihh,
    const unsigned short* __restrict__ whhh,
    const float* __restrict__ bih, const float* __restrict__ bhh,
    const unsigned short* __restrict__ mwihh,
    const float* __restrict__ mbih, const float* __restrict__ mbhh,
    const float* __restrict__ l1w, const float* __restrict__ l1b,
    const float* __restrict__ l3w, const float* __restrict__ l3b,
    float* __restrict__ out) {
  __shared__ __align__(16) unsigned xl[256 * 65];
  __shared__ __align__(16) unsigned qu[128];
  __shared__ __align__(16) float cst[128];
  __shared__ __align__(16) float gates[512];
  __shared__ __align__(16) float red[256];
  __shared__ __align__(16) float aw[256];
  int s = blockIdx.x, t = threadIdx.x, lane = t & 63, w = t >> 6;

  uint4 wreg[32], ureg[16];
  {
    const uint4* wp = (const uint4*)(wihh + (size_t)t * 256);
#pragma unroll
    for (int i = 0; i < 32; i++) wreg[i] = wp[i];
    const uint4* up = (const uint4*)(whhh + (size_t)t * 128);
#pragma unroll
    for (int i = 0; i < 16; i++) ureg[i] = up[i];
  }

  const uint4* xs4 = (const uint4*)(xb + (size_t)s * 32768);
#pragma unroll
  for (int it = 0; it < 8; it++) {
    int f = it * 512 + t;
    uint4 v = xs4[f];
    int n = f >> 4, jc = (f & 15) * 4;
    unsigned* dst = xl + n * 65 + jc;
    dst[0] = packh(uplo(v.x), uphi(v.x));
    dst[1] = packh(uplo(v.y), uphi(v.y));
    dst[2] = packh(uplo(v.z), uphi(v.z));
    dst[3] = packh(uplo(v.w), uphi(v.w));
  }
  if (t < 128) cst[t] = 0.f;
  __syncthreads();

  const uint4* q4 = (const uint4*)qu;
  float bsum = bih[t] + bhh[t];

  for (int step = 0; step < 6; step++) {
    if (step > 0) {
      float a0 = 0.f, a1 = 0.f, a2 = 0.f, a3 = 0.f;
#pragma unroll
      for (int i = 0; i < 16; i++) {
        uint4 qv = q4[i];
        a0 = fdot2u(wreg[i].x, qv.x, a0);
        a1 = fdot2u(wreg[i].y, qv.y, a1);
        a2 = fdot2u(wreg[i].z, qv.z, a2);
        a3 = fdot2u(wreg[i].w, qv.w, a3);
        a0 = fdot2u(ureg[i].x, qv.x, a0);
        a1 = fdot2u(ureg[i].y, qv.y, a1);
        a2 = fdot2u(ureg[i].z, qv.z, a2);
        a3 = fdot2u(ureg[i].w, qv.w, a3);
      }
#pragma unroll
      for (int i = 16; i < 32; i++) {
        uint4 qv = q4[i];
        a0 = fdot2u(wreg[i].x, qv.x, a0);
        a1 = fdot2u(wreg[i].y, qv.y, a1);
        a2 = fdot2u(wreg[i].z, qv.z, a2);
        a3 = fdot2u(wreg[i].w, qv.w, a3);
      }
      gates[t] = bsum + ((a0 + a1) + (a2 + a3));
    } else {
      gates[t] = bsum;
    }
    __syncthreads();
    if (t < 128) {
      float ig = sigf(gates[t]), fg = sigf(gates[128 + t]);
      float gg = tanhf(gates[256 + t]), og = sigf(gates[384 + t]);
      float cn = fg * cst[t] + ig * gg;
      cst[t] = cn;
      float hn = og * tanhf(cn);
      float hp = __shfl_xor(hn, 1, 64);
      if ((t & 1) == 0) qu[t >> 1] = packh(hn, hp);
    }
    __syncthreads();
    if (step > 0) {
      int n = t >> 1, p = t & 1;
      const unsigned* xr = xl + n * 65 + p * 32;
      float e0 = 0.f, e1 = 0.f;
#pragma unroll 8
      for (int i = 0; i < 32; i += 2) {
        e0 = fdot2u(xr[i], qu[p * 32 + i], e0);
        e1 = fdot2u(xr[i + 1], qu[p * 32 + i + 1], e1);
      }
      float e = e0 + e1;
      e += __shfl_xor(e, 1, 64);
      if (p == 0) red[n] = e;
      __syncthreads();
      float v0 = red[lane], v1 = red[64 + lane];
      float v2 = red[128 + lane], v3 = red[192 + lane];
      float m = fmaxf(fmaxf(v0, v1), fmaxf(v2, v3));
#pragma unroll
      for (int d = 1; d < 64; d <<= 1) m = fmaxf(m, __shfl_xor(m, d, 64));
      float p0 = expf(v0 - m), p1 = expf(v1 - m);
      float p2 = expf(v2 - m), p3 = expf(v3 - m);
      float ss = p0 + p1 + p2 + p3;
#pragma unroll
      for (int d = 1; d < 64; d <<= 1) ss += __shfl_xor(ss, d, 64);
      float Sinv = 1.f / ss;
      if (w == 0) {
        aw[lane] = p0 * Sinv; aw[64 + lane] = p1 * Sinv;
        aw[128 + lane] = p2 * Sinv; aw[192 + lane] = p3 * Sinv;
      }
    } else {
      if (t < 256) aw[t] = 1.f / 256.f;
    }
    __syncthreads();
    {
      int d = t & 127, grp = t >> 7;
      const unsigned* xc = xl + grp * 64 * 65 + (d >> 1);
      int hi = d & 1;
      const float* ap = aw + grp * 64;
      float r = 0.f;
#pragma unroll 8
      for (int n2 = 0; n2 < 64; n2++) {
        unsigned u = xc[n2 * 65];
        r += ap[n2] * (hi ? hhi(u) : hlo(u));
      }
      gates[t] = r;
    }
    __syncthreads();
    if (t < 128) {
      float rd = gates[t] + gates[128 + t] + gates[256 + t] + gates[384 + t];
      float rp = __shfl_xor(rd, 1, 64);
      if ((t & 1) == 0) qu[64 + (t >> 1)] = packh(rd, rp);
    }
    __syncthreads();
  }
  {
    float a0 = 0.f, a1 = 0.f, a2 = 0.f, a3 = 0.f;
    const uint4* mp = (const uint4*)(mwihh + (size_t)t * 256);
#pragma unroll 8
    for (int i = 0; i < 32; i++) {
      uint4 wv = mp[i], qv = q4[i];
      a0 = fdot2u(wv.x, qv.x, a0);
      a1 = fdot2u(wv.y, qv.y, a1);
      a2 = fdot2u(wv.z, qv.z, a2);
      a3 = fdot2u(wv.w, qv.w, a3);
    }
    gates[t] = mbih[t] + mbhh[t] + ((a0 + a1) + (a2 + a3));
  }
  __syncthreads();
  if (t < 128) {
    float ig = sigf(gates[t]);
    float gg = tanhf(gates[256 + t]);
    float og = sigf(gates[384 + t]);
    float cx = ig * gg;
    float hx = og * tanhf(cx);
    cst[t] = hx;
    out[64 + s * 128 + t] = hx;
    out[64 + 8192 + s * 128 + t] = cx;
  }
  __syncthreads();
  if (t < 128) {
    float acc = l1b[t];
    const float4* w4 = (const float4*)(l1w + (size_t)t * 128);
    const float4* h4 = (const float4*)cst;
#pragma unroll 8
    for (int k = 0; k < 32; k++) {
      float4 a = w4[k], b = h4[k];
      acc += a.x * b.x + a.y * b.y + a.z * b.z + a.w * b.w;
    }
    red[t] = fmaxf(acc, 0.f) * l3w[t];
  } else if (t < 256) {
    red[t] = 0.f;
  }
  __syncthreads();
  for (int off = 128; off; off >>= 1) {
    if (t < off) red[t] += red[t + off];
    __syncthreads();
  }
  if (t == 0) out[s] = red[0] + l3b[0];
}

// ---------------------------------------------------------------------------
extern "C" void kernel_launch(void* const* d_in, const int* in_sizes, int n_in,
                              void* d_out, int out_size, void* d_ws,
                              size_t ws_size, hipStream_t stream) {
  const float* data       = (const float*)d_in[0];
  const float* lin0_w     = (const float*)d_in[1];
  const float* lin0_b     = (const float*)d_in[2];
  const float* attn_in_w  = (const float*)d_in[3];
  const float* attn_in_b  = (const float*)d_in[4];
  const float* attn_out_w = (const float*)d_in[5];
  const float* attn_out_b = (const float*)d_in[6];
  const float* ln1_g      = (const float*)d_in[7];
  const float* ln1_b      = (const float*)d_in[8];
  const float* ff_w1      = (const float*)d_in[9];
  const float* ff_b1      = (const float*)d_in[10];
  const float* ff_w2      = (const float*)d_in[11];
  const float* ff_b2      = (const float*)d_in[12];
  const float* ln2_g      = (const float*)d_in[13];
  const float* ln2_b      = (const float*)d_in[14];
  const float* s2s_wih    = (const float*)d_in[15];
  const float* s2s_whh    = (const float*)d_in[16];
  const float* s2s_bih    = (const float*)d_in[17];
  const float* s2s_bhh    = (const float*)d_in[18];
  const float* mem_wih    = (const float*)d_in[19];
  const float* mem_bih    = (const float*)d_in[21];
  const float* mem_bhh    = (const float*)d_in[22];
  const float* lin1_w     = (const float*)d_in[23];
  const float* lin1_b     = (const float*)d_in[24];
  const float* lin3_w     = (const float*)d_in[25];
  const float* lin3_b     = (const float*)d_in[26];
  float* out = (float*)d_out;

  char* p = (char*)d_ws;
  float* x = (float*)p;                      p += (size_t)16384 * 128 * 4;
  unsigned short* xb = (unsigned short*)p;   p += (size_t)16384 * 128 * 2;
  unsigned short* wqkv = (unsigned short*)p; p += (size_t)294912 * 2;
  unsigned short* wout = (unsigned short*)p; p += (size_t)98304 * 2;
  unsigned short* w1b = (unsigned short*)p;  p += (size_t)1572864 * 2;
  unsigned short* w2h = (unsigned short*)p;  p += (size_t)1572864 * 2;
  unsigned short* wihh = (unsigned short*)p; p += (size_t)131072 * 2;
  unsigned short* whhh = (unsigned short*)p; p += (size_t)65536 * 2;
  unsigned short* mwihh = (unsigned short*)p; p += (size_t)131072 * 2;

  convw_kernel<<<15104, 256, 0, stream>>>(
      attn_in_w, attn_out_w, ff_w1, ff_w2, s2s_wih, s2s_whh, mem_wih,
      wqkv, wout, w1b, w2h, wihh, whhh, mwihh);
  lin0_kernel<<<8192, 256, 0, stream>>>(data, lin0_w, lin0_b, x, xb);

  for (int l = 0; l < 6; l++) {
    layer_kernel<<<256, 512, 0, stream>>>(
        xb, wqkv + (size_t)l * 49152, attn_in_b + l * 384,
        wout + (size_t)l * 16384, attn_out_b + l * 128,
        ln1_g + l * 128, ln1_b + l * 128,
        w1b + (size_t)l * 262144, ff_b1 + l * 2048,
        w2h + (size_t)l * 262144, ff_b2 + l * 128,
        ln2_g + l * 128, ln2_b + l * 128, x, xb);
  }

  s2s_kernel<<<64, 512, 0, stream>>>(
      xb, wihh, whhh, s2s_bih, s2s_bhh,
      mwihh, mem_bih, mem_bhh, lin1_w, lin1_b, lin3_w, lin3_b, out);
}

// Round 9
// 487.884 us; speedup vs baseline: 1.0868x; 1.0868x over previous
//
#include <hip/hip_runtime.h>
#include <math.h>

// S=64 segments(seq), B=256 atoms(batch), N=16384 rows, D=128, H=8, HD=16,
// DFF=2048, NL=6.  One fused kernel per transformer layer (R7 structure:
// GEMM-based FFN with Hs round-trip — R8's chained-MFMA FFN regressed).
// R9: Hs XOR-swizzled (fixes 8-way read conflicts), X-fragments hoisted to
// registers (invariant across FFN chunks / attention phases 1-2).

typedef __attribute__((ext_vector_type(8))) short bf16x8;
typedef __attribute__((ext_vector_type(4))) float f32x4;
typedef _Float16 __attribute__((ext_vector_type(2))) h16x2;

__device__ __forceinline__ unsigned short f2bf(float f) {
  union { float f; unsigned u; } x; x.f = f;
  unsigned r = x.u + 0x7fff + ((x.u >> 16) & 1);
  return (unsigned short)(r >> 16);
}
__device__ __forceinline__ float uplo(unsigned u) {
  union { unsigned u; float f; } x; x.u = u << 16; return x.f;
}
__device__ __forceinline__ float uphi(unsigned u) {
  union { unsigned u; float f; } x; x.u = u & 0xffff0000u; return x.f;
}
__device__ __forceinline__ unsigned short f2h(float f) {
  union { _Float16 h; unsigned short s; } x; x.h = (_Float16)f; return x.s;
}
__device__ __forceinline__ unsigned packh(float a, float b) {
  return (unsigned)f2h(a) | ((unsigned)f2h(b) << 16);
}
__device__ __forceinline__ float hlo(unsigned u) {
  union { unsigned short s; _Float16 h; } x; x.s = (unsigned short)(u & 0xffff);
  return (float)x.h;
}
__device__ __forceinline__ float hhi(unsigned u) {
  union { unsigned short s; _Float16 h; } x; x.s = (unsigned short)(u >> 16);
  return (float)x.h;
}
__device__ __forceinline__ float fdot2u(unsigned a, unsigned b, float c) {
#if __has_builtin(__builtin_amdgcn_fdot2)
  union U { unsigned u; h16x2 h; };
  U x, y; x.u = a; y.u = b;
  return __builtin_amdgcn_fdot2(x.h, y.h, c, false);
#else
  return c + hlo(a) * hlo(b) + hhi(a) * hhi(b);
#endif
}
__device__ __forceinline__ float sigf(float x) { return 1.f / (1.f + expf(-x)); }

// async 16B global->LDS; LDS base wave-uniform (+ lane*16 implicit).
__device__ __forceinline__ void gl2lds16(const void* g, void* l) {
  __builtin_amdgcn_global_load_lds(
      (const __attribute__((address_space(1))) unsigned int*)g,
      (__attribute__((address_space(3))) unsigned int*)l, 16, 0, 0);
}

// ---------------------------------------------------------------------------
// weight conversion: bf16 for MFMA GEMMs, f16 for the s2s tail.
// aiw 294912 | aow 98304 | w1 1572864 | w2 1572864 (bf16)
// | wih 131072 | whh 65536 | mwih 131072 (f16)   -> total 3866624
// ---------------------------------------------------------------------------
__global__ __launch_bounds__(256) void convw_kernel(
    const float* __restrict__ aiw, const float* __restrict__ aow,
    const float* __restrict__ w1, const float* __restrict__ w2,
    const float* __restrict__ wih, const float* __restrict__ whh,
    const float* __restrict__ mwih,
    unsigned short* __restrict__ o0, unsigned short* __restrict__ o1,
    unsigned short* __restrict__ o2, unsigned short* __restrict__ o3,
    unsigned short* __restrict__ o4, unsigned short* __restrict__ o5,
    unsigned short* __restrict__ o6) {
  int i = blockIdx.x * 256 + threadIdx.x;
  if (i < 294912) {
    o0[i] = f2bf(aiw[i]);
  } else if (i < 393216) {
    int j = i - 294912; o1[j] = f2bf(aow[j]);
  } else if (i < 1966080) {
    int j = i - 393216; o2[j] = f2bf(w1[j]);
  } else if (i < 3538944) {
    int j = i - 1966080; o3[j] = f2bf(w2[j]);
  } else if (i < 3670016) {
    int j = i - 3538944; o4[j] = f2h(wih[j]);
  } else if (i < 3735552) {
    int j = i - 3670016; o5[j] = f2h(whh[j]);
  } else {
    int j = i - 3735552; o6[j] = f2h(mwih[j]);
  }
}

// ---------------------------------------------------------------------------
// lin0: x = relu(data @ w^T + b), writes fp32 x and bf16 xb
// ---------------------------------------------------------------------------
__global__ __launch_bounds__(256) void lin0_kernel(
    const float* __restrict__ data, const float* __restrict__ w,
    const float* __restrict__ b, float* __restrict__ x,
    unsigned short* __restrict__ xb) {
  int i = blockIdx.x * 256 + threadIdx.x;
  int n = i >> 7, d = i & 127;
  float v = b[d] + data[n * 3 + 0] * w[d * 3 + 0]
                 + data[n * 3 + 1] * w[d * 3 + 1]
                 + data[n * 3 + 2] * w[d * 3 + 2];
  v = fmaxf(v, 0.0f);
  x[i] = v;
  xb[i] = f2bf(v);
}

// ---------------------------------------------------------------------------
// Fused transformer LAYER: block = atom b (256 blocks), 512 threads, 8 waves.
// ---------------------------------------------------------------------------
__global__ __launch_bounds__(512) void layer_kernel(
    const unsigned short* __restrict__ xbg,
    const unsigned short* __restrict__ wqkv, const float* __restrict__ bqkv,
    const unsigned short* __restrict__ wout, const float* __restrict__ bout,
    const float* __restrict__ ln1g, const float* __restrict__ ln1b,
    const unsigned short* __restrict__ w1, const float* __restrict__ b1,
    const unsigned short* __restrict__ w2, const float* __restrict__ b2,
    const float* __restrict__ ln2g, const float* __restrict__ ln2b,
    float* __restrict__ xio, unsigned short* __restrict__ xbo) {
  __shared__ __align__(16) unsigned short Xs[64 * 128];   // 16 KB
  __shared__ __align__(16) unsigned short Ws[256 * 128];  // 64 KB
  __shared__ __align__(16) unsigned short U1[128 * 128];  // 32 KB
  __shared__ __align__(16) unsigned short U2[128 * 128];  // 32 KB
  __shared__ __align__(16) uint4 zchunk;
  __shared__ float psum[8][64], psq[8][64];
  __shared__ float2 stats[64];

  unsigned short* Qs = U1;            // 64x128
  unsigned short* Ks2 = U1 + 8192;    // 64x128
  unsigned short* VT = U2;            // 128x64
  unsigned short* AOs = U2 + 8192;    // 64x128
  unsigned short* Hs = U2;            // 64x128 swizzled (FFN)

  int tid = threadIdx.x, w = tid >> 6, lane = tid & 63;
  int b = blockIdx.x;
  int r4 = lane >> 4, cs = lane & 15;
  int fr = lane & 15, fq = lane >> 4;

  if (tid == 0) zchunk = make_uint4(0u, 0u, 0u, 0u);

  // ---- phase 0: stage x tile + Wq+Wk (wqkv rows 0..255) ----
#pragma unroll
  for (int i = 0; i < 2; i++) {
    int issue = w * 2 + i;
    int row = issue * 4 + r4;  // s index
    int g = cs ^ (row & 7);
    gl2lds16(xbg + (size_t)(row * 256 + b) * 128 + g * 8,
             (char*)Xs + issue * 1024);
  }
#pragma unroll
  for (int i = 0; i < 8; i++) {
    int issue = w * 8 + i;
    int row = issue * 4 + r4;
    int g = cs ^ (row & 7);
    gl2lds16(wqkv + (size_t)row * 128 + g * 8, (char*)Ws + issue * 1024);
  }
  __syncthreads();

  // hoisted x A-fragments (shared by phases 1 and 2)
  bf16x8 xfragA[4][4];
#pragma unroll
  for (int ks = 0; ks < 4; ks++)
#pragma unroll
    for (int mi = 0; mi < 4; mi++) {
      int row = mi * 16 + fr;
      int kq = (ks * 4 + fq) ^ (row & 7);
      xfragA[ks][mi] = *(const bf16x8*)(Xs + row * 128 + kq * 8);
    }

  // ---- phase 1: Q,K = x @ Wqk^T + bias -> Qs/Ks2 ----
  {
    f32x4 acc[4][2];
#pragma unroll
    for (int i = 0; i < 4; i++)
#pragma unroll
      for (int j = 0; j < 2; j++) acc[i][j] = (f32x4){0.f, 0.f, 0.f, 0.f};
#pragma unroll
    for (int ks = 0; ks < 4; ks++) {
      bf16x8 bf[2];
#pragma unroll
      for (int ni = 0; ni < 2; ni++) {
        int wr = (w * 2 + ni) * 16 + fr;
        int kq = (ks * 4 + fq) ^ (wr & 7);
        bf[ni] = *(const bf16x8*)(Ws + wr * 128 + kq * 8);
      }
#pragma unroll
      for (int mi = 0; mi < 4; mi++)
#pragma unroll
        for (int ni = 0; ni < 2; ni++)
          acc[mi][ni] = __builtin_amdgcn_mfma_f32_16x16x32_bf16(
              xfragA[ks][mi], bf[ni], acc[mi][ni], 0, 0, 0);
    }
#pragma unroll
    for (int ni = 0; ni < 2; ni++) {
      int c = (w * 2 + ni) * 16 + fr;  // 0..255
      float bv = bqkv[c];
      unsigned short* dst = (c < 128) ? Qs : Ks2;
      int cc = c & 127;
#pragma unroll
      for (int mi = 0; mi < 4; mi++)
#pragma unroll
        for (int r = 0; r < 4; r++) {
          int row = mi * 16 + fq * 4 + r;
          dst[row * 128 + (((cc >> 3) ^ (row & 7)) << 3) + (cc & 7)] =
              f2bf(acc[mi][ni][r] + bv);
        }
    }
  }
  __syncthreads();

  // ---- stage Wv (wqkv rows 256..383) into Ws rows 0..127 ----
#pragma unroll
  for (int i = 0; i < 4; i++) {
    int issue = w * 4 + i;
    int row = issue * 4 + r4;
    int g = cs ^ (row & 7);
    gl2lds16(wqkv + (size_t)(256 + row) * 128 + g * 8, (char*)Ws + issue * 1024);
  }
  __syncthreads();

  // ---- phase 2: V = x @ Wv^T + bias -> VT[feature][s] ----
  {
    f32x4 acc[4];
#pragma unroll
    for (int i = 0; i < 4; i++) acc[i] = (f32x4){0.f, 0.f, 0.f, 0.f};
#pragma unroll
    for (int ks = 0; ks < 4; ks++) {
      bf16x8 bf;
      {
        int wr = w * 16 + fr;
        int kq = (ks * 4 + fq) ^ (wr & 7);
        bf = *(const bf16x8*)(Ws + wr * 128 + kq * 8);
      }
#pragma unroll
      for (int mi = 0; mi < 4; mi++)
        acc[mi] = __builtin_amdgcn_mfma_f32_16x16x32_bf16(xfragA[ks][mi], bf,
                                                          acc[mi], 0, 0, 0);
    }
    int f = w * 16 + fr;
    float bv = bqkv[256 + f];
#pragma unroll
    for (int mi = 0; mi < 4; mi++)
#pragma unroll
      for (int r = 0; r < 4; r++) {
        int srow = mi * 16 + fq * 4 + r;
        VT[f * 64 + (((srow >> 3) ^ (f & 7)) << 3) + (srow & 7)] =
            f2bf(acc[mi][r] + bv);
      }
  }
  __syncthreads();

  // ---- phase 3: per-wave head attention (head h = w), P in Ws ----
  {
    int h = w;
    unsigned short* Pb = Ws + w * 4096;  // 8 KB per wave
    f32x4 sc[4][4];
#pragma unroll
    for (int i = 0; i < 4; i++)
#pragma unroll
      for (int j = 0; j < 4; j++) sc[i][j] = (f32x4){0.f, 0.f, 0.f, 0.f};
    {
      bf16x8 af[4], bf[4];
#pragma unroll
      for (int mi = 0; mi < 4; mi++) {
        int row = mi * 16 + fr;
        const unsigned short* pa =
            (fq < 2) ? (Qs + row * 128 + (((h * 2 + fq) ^ (row & 7)) << 3))
                     : (const unsigned short*)&zchunk;
        af[mi] = *(const bf16x8*)pa;
      }
#pragma unroll
      for (int ti = 0; ti < 4; ti++) {
        int trow = ti * 16 + fr;
        const unsigned short* pb =
            (fq < 2) ? (Ks2 + trow * 128 + (((h * 2 + fq) ^ (trow & 7)) << 3))
                     : (const unsigned short*)&zchunk;
        bf[ti] = *(const bf16x8*)pb;
      }
#pragma unroll
      for (int mi = 0; mi < 4; mi++)
#pragma unroll
        for (int ti = 0; ti < 4; ti++)
          sc[mi][ti] = __builtin_amdgcn_mfma_f32_16x16x32_bf16(
              af[mi], bf[ti], sc[mi][ti], 0, 0, 0);
    }
#pragma unroll
    for (int mi = 0; mi < 4; mi++) {
#pragma unroll
      for (int r = 0; r < 4; r++) {
        float m = -1e30f;
#pragma unroll
        for (int ti = 0; ti < 4; ti++) m = fmaxf(m, sc[mi][ti][r]);
        m = fmaxf(m, __shfl_xor(m, 1, 64));
        m = fmaxf(m, __shfl_xor(m, 2, 64));
        m = fmaxf(m, __shfl_xor(m, 4, 64));
        m = fmaxf(m, __shfl_xor(m, 8, 64));
        m *= 0.25f;
        float ss = 0.f;
#pragma unroll
        for (int ti = 0; ti < 4; ti++) {
          float p = expf(sc[mi][ti][r] * 0.25f - m);
          sc[mi][ti][r] = p;
          ss += p;
        }
        ss += __shfl_xor(ss, 1, 64);
        ss += __shfl_xor(ss, 2, 64);
        ss += __shfl_xor(ss, 4, 64);
        ss += __shfl_xor(ss, 8, 64);
        float inv = 1.f / ss;
        int prow = mi * 16 + fq * 4 + r;
#pragma unroll
        for (int ti = 0; ti < 4; ti++) {
          int t = ti * 16 + fr;
          Pb[prow * 64 + (((t >> 3) ^ (prow & 7)) << 3) + (t & 7)] =
              f2bf(sc[mi][ti][r] * inv);
        }
      }
    }
    // PV
    f32x4 po[4];
#pragma unroll
    for (int i = 0; i < 4; i++) po[i] = (f32x4){0.f, 0.f, 0.f, 0.f};
#pragma unroll
    for (int ks2 = 0; ks2 < 2; ks2++) {
      bf16x8 af[4], bf;
#pragma unroll
      for (int si = 0; si < 4; si++) {
        int prow = si * 16 + fr;
        int kq = (ks2 * 4 + fq) ^ (prow & 7);
        af[si] = *(const bf16x8*)(Pb + prow * 64 + kq * 8);
      }
      {
        int vrow = h * 16 + fr;
        int kq = (ks2 * 4 + fq) ^ (vrow & 7);
        bf = *(const bf16x8*)(VT + vrow * 64 + kq * 8);
      }
#pragma unroll
      for (int si = 0; si < 4; si++)
        po[si] = __builtin_amdgcn_mfma_f32_16x16x32_bf16(af[si], bf, po[si],
                                                         0, 0, 0);
    }
#pragma unroll
    for (int si = 0; si < 4; si++)
#pragma unroll
      for (int r = 0; r < 4; r++) {
        int arow = si * 16 + fq * 4 + r;
        int c = h * 16 + fr;
        AOs[arow * 128 + (((c >> 3) ^ (arow & 7)) << 3) + (c & 7)] =
            f2bf(po[si][r]);
      }
  }
  __syncthreads();

  // ---- stage Wout into Ws rows 0..127 ----
#pragma unroll
  for (int i = 0; i < 4; i++) {
    int issue = w * 4 + i;
    int row = issue * 4 + r4;
    int g = cs ^ (row & 7);
    gl2lds16(wout + (size_t)row * 128 + g * 8, (char*)Ws + issue * 1024);
  }
  __syncthreads();

  // ---- phase 4: v = x + ao @ Wout^T + bias ; LN1 -> Xs (bf16) ----
  {
    f32x4 acc[4];
#pragma unroll
    for (int i = 0; i < 4; i++) acc[i] = (f32x4){0.f, 0.f, 0.f, 0.f};
#pragma unroll
    for (int ks = 0; ks < 4; ks++) {
      bf16x8 af[4], bf;
#pragma unroll
      for (int si = 0; si < 4; si++) {
        int row = si * 16 + fr;
        int kq = (ks * 4 + fq) ^ (row & 7);
        af[si] = *(const bf16x8*)(AOs + row * 128 + kq * 8);
      }
      {
        int wr = w * 16 + fr;
        int kq = (ks * 4 + fq) ^ (wr & 7);
        bf = *(const bf16x8*)(Ws + wr * 128 + kq * 8);
      }
#pragma unroll
      for (int si = 0; si < 4; si++)
        acc[si] = __builtin_amdgcn_mfma_f32_16x16x32_bf16(af[si], bf, acc[si],
                                                          0, 0, 0);
    }
    int c = w * 16 + fr;
    float bv = bout[c];
    float vv4[4][4];
    float sums[4][4], sqs[4][4];
#pragma unroll
    for (int si = 0; si < 4; si++)
#pragma unroll
      for (int r = 0; r < 4; r++) {
        int row = si * 16 + fq * 4 + r;
        float v = acc[si][r] + bv + xio[(size_t)(row * 256 + b) * 128 + c];
        vv4[si][r] = v;
        sums[si][r] = v;
        sqs[si][r] = v * v;
      }
#pragma unroll
    for (int d = 1; d < 16; d <<= 1) {
#pragma unroll
      for (int si = 0; si < 4; si++)
#pragma unroll
        for (int r = 0; r < 4; r++) {
          sums[si][r] += __shfl_xor(sums[si][r], d, 64);
          sqs[si][r] += __shfl_xor(sqs[si][r], d, 64);
        }
    }
    if (fr == 0) {
#pragma unroll
      for (int si = 0; si < 4; si++)
#pragma unroll
        for (int r = 0; r < 4; r++) {
          int row = si * 16 + fq * 4 + r;
          psum[w][row] = sums[si][r];
          psq[w][row] = sqs[si][r];
        }
    }
    __syncthreads();  // A: phase-4 mfma done everywhere -> Ws/U1 reusable

    // FFN prologue staging: W1(0)->Ws[0], W2(0)->U1 (drains at barrier B)
#pragma unroll
    for (int i = 0; i < 4; i++) {
      int issue = w * 4 + i;
      int row = issue * 4 + r4;
      int g = cs ^ (row & 7);
      gl2lds16(w1 + (size_t)row * 128 + g * 8, (char*)Ws + issue * 1024);
      gl2lds16(w2 + (size_t)row * 2048 + g * 8, (char*)U1 + issue * 1024);
    }
    if (tid < 64) {
      float S = 0.f, Q = 0.f;
#pragma unroll
      for (int ww = 0; ww < 8; ww++) { S += psum[ww][tid]; Q += psq[ww][tid]; }
      float m = S * (1.f / 128.f);
      float var = Q * (1.f / 128.f) - m * m;
      stats[tid] = make_float2(m, rsqrtf(var + 1e-5f));
    }
    __syncthreads();  // B
    float gl = ln1g[c], bl = ln1b[c];
#pragma unroll
    for (int si = 0; si < 4; si++)
#pragma unroll
      for (int r = 0; r < 4; r++) {
        int row = si * 16 + fq * 4 + r;
        float2 st2 = stats[row];
        float y = (vv4[si][r] - st2.x) * st2.y * gl + bl;
        Xs[row * 128 + (((c >> 3) ^ (row & 7)) << 3) + (c & 7)] = f2bf(y);
      }
  }
  __syncthreads();  // C: Xs (LN1 output) published; W1(0)/W2(0) drained

  // hoisted FFN x A-fragments (invariant across all 16 chunks)
  bf16x8 xfragF[4][4];
#pragma unroll
  for (int ks = 0; ks < 4; ks++)
#pragma unroll
    for (int mi = 0; mi < 4; mi++) {
      int row = mi * 16 + fr;
      int kq = (ks * 4 + fq) ^ (row & 7);
      xfragF[ks][mi] = *(const bf16x8*)(Xs + row * 128 + kq * 8);
    }

  // ---- FFN chunk loop: 16 chunks of 128 hidden, 8 waves x 16 cols ----
  f32x4 acc2[4];
#pragma unroll
  for (int i = 0; i < 4; i++) acc2[i] = (f32x4){0.f, 0.f, 0.f, 0.f};

  for (int c = 0; c < 16; c++) {
    const unsigned short* W1cur = Ws + (c & 1) * 16384;
    // ff1: wave w -> hidden cols [w*16, w*16+16)
    f32x4 acc1[4];
#pragma unroll
    for (int i = 0; i < 4; i++) acc1[i] = (f32x4){0.f, 0.f, 0.f, 0.f};
#pragma unroll
    for (int ks = 0; ks < 4; ks++) {
      bf16x8 bf;
      {
        int row = w * 16 + fr;
        int kq = (ks * 4 + fq) ^ (row & 7);
        bf = *(const bf16x8*)(W1cur + row * 128 + kq * 8);
      }
#pragma unroll
      for (int mi = 0; mi < 4; mi++)
        acc1[mi] = __builtin_amdgcn_mfma_f32_16x16x32_bf16(xfragF[ks][mi], bf,
                                                           acc1[mi], 0, 0, 0);
    }
    // prefetch W1(c+1)
    if (c < 15) {
#pragma unroll
      for (int i = 0; i < 4; i++) {
        int issue = w * 4 + i;
        int row = issue * 4 + r4;
        int g = cs ^ (row & 7);
        gl2lds16(w1 + (size_t)((c + 1) * 128 + row) * 128 + g * 8,
                 (char*)Ws + ((c + 1) & 1) * 32768 + issue * 1024);
      }
    }
    // bias + relu -> Hs (bf16, XOR-swizzled 128-stride)
    {
      int col = w * 16 + fr;
      float bv = b1[c * 128 + col];
#pragma unroll
      for (int mi = 0; mi < 4; mi++)
#pragma unroll
        for (int r = 0; r < 4; r++) {
          int row = mi * 16 + fq * 4 + r;
          Hs[row * 128 + (((col >> 3) ^ (row & 7)) << 3) + (col & 7)] =
              f2bf(fmaxf(acc1[mi][r] + bv, 0.f));
        }
    }
    __syncthreads();  // B1: Hs visible; drains W2(c)/W1(c+1)

    // ff2: wave w -> out cols [w*16, w*16+16)
#pragma unroll
    for (int ks = 0; ks < 4; ks++) {
      bf16x8 af[4], bf;
#pragma unroll
      for (int si = 0; si < 4; si++) {
        int row = si * 16 + fr;
        int kq = (ks * 4 + fq) ^ (row & 7);
        af[si] = *(const bf16x8*)(Hs + row * 128 + kq * 8);
      }
      {
        int row = w * 16 + fr;
        int kq = (ks * 4 + fq) ^ (row & 7);
        bf = *(const bf16x8*)(U1 + row * 128 + kq * 8);
      }
#pragma unroll
      for (int si = 0; si < 4; si++)
        acc2[si] = __builtin_amdgcn_mfma_f32_16x16x32_bf16(af[si], bf, acc2[si],
                                                           0, 0, 0);
    }
    __syncthreads();  // B2: U1/Hs reusable
    // stage W2(c+1) (overlaps next ff1)
    if (c < 15) {
#pragma unroll
      for (int i = 0; i < 4; i++) {
        int issue = w * 4 + i;
        int row = issue * 4 + r4;
        int g = cs ^ (row & 7);
        gl2lds16(w2 + (size_t)row * 2048 + (c + 1) * 128 + g * 8,
                 (char*)U1 + issue * 1024);
      }
    }
  }

  // ---- FFN epilogue: +b2 + residual (from Xs), LN2, write global ----
  {
    int c = w * 16 + fr;
    float bv = b2[c];
    float vv4[4][4];
    float sums[4][4], sqs[4][4];
#pragma unroll
    for (int si = 0; si < 4; si++)
#pragma unroll
      for (int r = 0; r < 4; r++) {
        int row = si * 16 + fq * 4 + r;
        float resid = uplo((unsigned)
            Xs[row * 128 + (((c >> 3) ^ (row & 7)) << 3) + (c & 7)]);
        float v = acc2[si][r] + bv + resid;
        vv4[si][r] = v;
        sums[si][r] = v;
        sqs[si][r] = v * v;
      }
#pragma unroll
    for (int d = 1; d < 16; d <<= 1) {
#pragma unroll
      for (int si = 0; si < 4; si++)
#pragma unroll
        for (int r = 0; r < 4; r++) {
          sums[si][r] += __shfl_xor(sums[si][r], d, 64);
          sqs[si][r] += __shfl_xor(sqs[si][r], d, 64);
        }
    }
    if (fr == 0) {
#pragma unroll
      for (int si = 0; si < 4; si++)
#pragma unroll
        for (int r = 0; r < 4; r++) {
          int row = si * 16 + fq * 4 + r;
          psum[w][row] = sums[si][r];
          psq[w][row] = sqs[si][r];
        }
    }
    __syncthreads();
    if (tid < 64) {
      float S = 0.f, Q = 0.f;
#pragma unroll
      for (int ww = 0; ww < 8; ww++) { S += psum[ww][tid]; Q += psq[ww][tid]; }
      float m = S * (1.f / 128.f);
      float var = Q * (1.f / 128.f) - m * m;
      stats[tid] = make_float2(m, rsqrtf(var + 1e-5f));
    }
    __syncthreads();
    float gl = ln2g[c], bl = ln2b[c];
#pragma unroll
    for (int si = 0; si < 4; si++)
#pragma unroll
      for (int r = 0; r < 4; r++) {
        int row = si * 16 + fq * 4 + r;
        float2 st = stats[row];
        float y = (vv4[si][r] - st.x) * st.y * gl + bl;
        size_t o = (size_t)(row * 256 + b) * 128 + c;
        xio[o] = y;
        xbo[o] = f2bf(y);
      }
  }
}

// ---------------------------------------------------------------------------
// Set2Set (6 steps) + memory LSTM + lin1 + lin3. One 512-thread block per
// segment (64 blocks -> 1/CU). (512,1): 256-VGPR cap keeps the 48 uint4 gate
// weights register-resident.
// ---------------------------------------------------------------------------
__global__ __launch_bounds__(512, 1) void s2s_kernel(
    const unsigned short* __restrict__ xb,
    const unsigned short* __restrict__ wihh,
    const unsigned short* __restrict__ whhh,
    const float* __restrict__ bih, const float* __restrict__ bhh,
    const unsigned short* __restrict__ mwihh,
    const float* __restrict__ mbih, const float* __restrict__ mbhh,
    const float* __restrict__ l1w, const float* __restrict__ l1b,
    const float* __restrict__ l3w, const float* __restrict__ l3b,
    float* __restrict__ out) {
  __shared__ __align__(16) unsigned xl[256 * 65];
  __shared__ __align__(16) unsigned qu[128];
  __shared__ __align__(16) float cst[128];
  __shared__ __align__(16) float gates[512];
  __shared__ __align__(16) float red[256];
  __shared__ __align__(16) float aw[256];
  int s = blockIdx.x, t = threadIdx.x, lane = t & 63, w = t >> 6;

  uint4 wreg[32], ureg[16];
  {
    const uint4* wp = (const uint4*)(wihh + (size_t)t * 256);
#pragma unroll
    for (int i = 0; i < 32; i++) wreg[i] = wp[i];
    const uint4* up = (const uint4*)(whhh + (size_t)t * 128);
#pragma unroll
    for (int i = 0; i < 16; i++) ureg[i] = up[i];
  }

  const uint4* xs4 = (const uint4*)(xb + (size_t)s * 32768);
#pragma unroll
  for (int it = 0; it < 8; it++) {
    int f = it * 512 + t;
    uint4 v = xs4[f];
    int n = f >> 4, jc = (f & 15) * 4;
    unsigned* dst = xl + n * 65 + jc;
    dst[0] = packh(uplo(v.x), uphi(v.x));
    dst[1] = packh(uplo(v.y), uphi(v.y));
    dst[2] = packh(uplo(v.z), uphi(v.z));
    dst[3] = packh(uplo(v.w), uphi(v.w));
  }
  if (t < 128) cst[t] = 0.f;
  __syncthreads();

  const uint4* q4 = (const uint4*)qu;
  float bsum = bih[t] + bhh[t];

  for (int step = 0; step < 6; step++) {
    if (step > 0) {
      float a0 = 0.f, a1 = 0.f, a2 = 0.f, a3 = 0.f;
#pragma unroll
      for (int i = 0; i < 16; i++) {
        uint4 qv = q4[i];
        a0 = fdot2u(wreg[i].x, qv.x, a0);
        a1 = fdot2u(wreg[i].y, qv.y, a1);
        a2 = fdot2u(wreg[i].z, qv.z, a2);
        a3 = fdot2u(wreg[i].w, qv.w, a3);
        a0 = fdot2u(ureg[i].x, qv.x, a0);
        a1 = fdot2u(ureg[i].y, qv.y, a1);
        a2 = fdot2u(ureg[i].z, qv.z, a2);
        a3 = fdot2u(ureg[i].w, qv.w, a3);
      }
#pragma unroll
      for (int i = 16; i < 32; i++) {
        uint4 qv = q4[i];
        a0 = fdot2u(wreg[i].x, qv.x, a0);
        a1 = fdot2u(wreg[i].y, qv.y, a1);
        a2 = fdot2u(wreg[i].z, qv.z, a2);
        a3 = fdot2u(wreg[i].w, qv.w, a3);
      }
      gates[t] = bsum + ((a0 + a1) + (a2 + a3));
    } else {
      gates[t] = bsum;
    }
    __syncthreads();
    if (t < 128) {
      float ig = sigf(gates[t]), fg = sigf(gates[128 + t]);
      float gg = tanhf(gates[256 + t]), og = sigf(gates[384 + t]);
      float cn = fg * cst[t] + ig * gg;
      cst[t] = cn;
      float hn = og * tanhf(cn);
      float hp = __shfl_xor(hn, 1, 64);
      if ((t & 1) == 0) qu[t >> 1] = packh(hn, hp);
    }
    __syncthreads();
    if (step > 0) {
      int n = t >> 1, p = t & 1;
      const unsigned* xr = xl + n * 65 + p * 32;
      float e0 = 0.f, e1 = 0.f;
#pragma unroll 8
      for (int i = 0; i < 32; i += 2) {
        e0 = fdot2u(xr[i], qu[p * 32 + i], e0);
        e1 = fdot2u(xr[i + 1], qu[p * 32 + i + 1], e1);
      }
      float e = e0 + e1;
      e += __shfl_xor(e, 1, 64);
      if (p == 0) red[n] = e;
      __syncthreads();
      float v0 = red[lane], v1 = red[64 + lane];
      float v2 = red[128 + lane], v3 = red[192 + lane];
      float m = fmaxf(fmaxf(v0, v1), fmaxf(v2, v3));
#pragma unroll
      for (int d = 1; d < 64; d <<= 1) m = fmaxf(m, __shfl_xor(m, d, 64));
      float p0 = expf(v0 - m), p1 = expf(v1 - m);
      float p2 = expf(v2 - m), p3 = expf(v3 - m);
      float ss = p0 + p1 + p2 + p3;
#pragma unroll
      for (int d = 1; d < 64; d <<= 1) ss += __shfl_xor(ss, d, 64);
      float Sinv = 1.f / ss;
      if (w == 0) {
        aw[lane] = p0 * Sinv; aw[64 + lane] = p1 * Sinv;
        aw[128 + lane] = p2 * Sinv; aw[192 + lane] = p3 * Sinv;
      }
    } else {
      if (t < 256) aw[t] = 1.f / 256.f;
    }
    __syncthreads();
    {
      int d = t & 127, grp = t >> 7;
      const unsigned* xc = xl + grp * 64 * 65 + (d >> 1);
      int hi = d & 1;
      const float* ap = aw + grp * 64;
      float r = 0.f;
#pragma unroll 8
      for (int n2 = 0; n2 < 64; n2++) {
        unsigned u = xc[n2 * 65];
        r += ap[n2] * (hi ? hhi(u) : hlo(u));
      }
      gates[t] = r;
    }
    __syncthreads();
    if (t < 128) {
      float rd = gates[t] + gates[128 + t] + gates[256 + t] + gates[384 + t];
      float rp = __shfl_xor(rd, 1, 64);
      if ((t & 1) == 0) qu[64 + (t >> 1)] = packh(rd, rp);
    }
    __syncthreads();
  }
  {
    float a0 = 0.f, a1 = 0.f, a2 = 0.f, a3 = 0.f;
    const uint4* mp = (const uint4*)(mwihh + (size_t)t * 256);
#pragma unroll 8
    for (int i = 0; i < 32; i++) {
      uint4 wv = mp[i], qv = q4[i];
      a0 = fdot2u(wv.x, qv.x, a0);
      a1 = fdot2u(wv.y, qv.y, a1);
      a2 = fdot2u(wv.z, qv.z, a2);
      a3 = fdot2u(wv.w, qv.w, a3);
    }
    gates[t] = mbih[t] + mbhh[t] + ((a0 + a1) + (a2 + a3));
  }
  __syncthreads();
  if (t < 128) {
    float ig = sigf(gates[t]);
    float gg = tanhf(gates[256 + t]);
    float og = sigf(gates[384 + t]);
    float cx = ig * gg;
    float hx = og * tanhf(cx);
    cst[t] = hx;
    out[64 + s * 128 + t] = hx;
    out[64 + 8192 + s * 128 + t] = cx;
  }
  __syncthreads();
  if (t < 128) {
    float acc = l1b[t];
    const float4* w4 = (const float4*)(l1w + (size_t)t * 128);
    const float4* h4 = (const float4*)cst;
#pragma unroll 8
    for (int k = 0; k < 32; k++) {
      float4 a = w4[k], b = h4[k];
      acc += a.x * b.x + a.y * b.y + a.z * b.z + a.w * b.w;
    }
    red[t] = fmaxf(acc, 0.f) * l3w[t];
  } else if (t < 256) {
    red[t] = 0.f;
  }
  __syncthreads();
  for (int off = 128; off; off >>= 1) {
    if (t < off) red[t] += red[t + off];
    __syncthreads();
  }
  if (t == 0) out[s] = red[0] + l3b[0];
}

// ---------------------------------------------------------------------------
extern "C" void kernel_launch(void* const* d_in, const int* in_sizes, int n_in,
                              void* d_out, int out_size, void* d_ws,
                              size_t ws_size, hipStream_t stream) {
  const float* data       = (const float*)d_in[0];
  const float* lin0_w     = (const float*)d_in[1];
  const float* lin0_b     = (const float*)d_in[2];
  const float* attn_in_w  = (const float*)d_in[3];
  const float* attn_in_b  = (const float*)d_in[4];
  const float* attn_out_w = (const float*)d_in[5];
  const float* attn_out_b = (const float*)d_in[6];
  const float* ln1_g      = (const float*)d_in[7];
  const float* ln1_b      = (const float*)d_in[8];
  const float* ff_w1      = (const float*)d_in[9];
  const float* ff_b1      = (const float*)d_in[10];
  const float* ff_w2      = (const float*)d_in[11];
  const float* ff_b2      = (const float*)d_in[12];
  const float* ln2_g      = (const float*)d_in[13];
  const float* ln2_b      = (const float*)d_in[14];
  const float* s2s_wih    = (const float*)d_in[15];
  const float* s2s_whh    = (const float*)d_in[16];
  const float* s2s_bih    = (const float*)d_in[17];
  const float* s2s_bhh    = (const float*)d_in[18];
  const float* mem_wih    = (const float*)d_in[19];
  const float* mem_bih    = (const float*)d_in[21];
  const float* mem_bhh    = (const float*)d_in[22];
  const float* lin1_w     = (const float*)d_in[23];
  const float* lin1_b     = (const float*)d_in[24];
  const float* lin3_w     = (const float*)d_in[25];
  const float* lin3_b     = (const float*)d_in[26];
  float* out = (float*)d_out;

  char* p = (char*)d_ws;
  float* x = (float*)p;                      p += (size_t)16384 * 128 * 4;
  unsigned short* xb = (unsigned short*)p;   p += (size_t)16384 * 128 * 2;
  unsigned short* wqkv = (unsigned short*)p; p += (size_t)294912 * 2;
  unsigned short* wout = (unsigned short*)p; p += (size_t)98304 * 2;
  unsigned short* w1b = (unsigned short*)p;  p += (size_t)1572864 * 2;
  unsigned short* w2b = (unsigned short*)p;  p += (size_t)1572864 * 2;
  unsigned short* wihh = (unsigned short*)p; p += (size_t)131072 * 2;
  unsigned short* whhh = (unsigned short*)p; p += (size_t)65536 * 2;
  unsigned short* mwihh = (unsigned short*)p; p += (size_t)131072 * 2;

  convw_kernel<<<15104, 256, 0, stream>>>(
      attn_in_w, attn_out_w, ff_w1, ff_w2, s2s_wih, s2s_whh, mem_wih,
      wqkv, wout, w1b, w2b, wihh, whhh, mwihh);
  lin0_kernel<<<8192, 256, 0, stream>>>(data, lin0_w, lin0_b, x, xb);

  for (int l = 0; l < 6; l++) {
    layer_kernel<<<256, 512, 0, stream>>>(
        xb, wqkv + (size_t)l * 49152, attn_in_b + l * 384,
        wout + (size_t)l * 16384, attn_out_b + l * 128,
        ln1_g + l * 128, ln1_b + l * 128,
        w1b + (size_t)l * 262144, ff_b1 + l * 2048,
        w2b + (size_t)l * 262144, ff_b2 + l * 128,
        ln2_g + l * 128, ln2_b + l * 128, x, xb);
  }

  s2s_kernel<<<64, 512, 0, stream>>>(
      xb, wihh, whhh, s2s_bih, s2s_bhh,
      mwihh, mem_bih, mem_bhh, lin1_w, lin1_b, lin3_w, lin3_b, out);
}